// Round 8
// baseline (483.181 us; speedup 1.0000x reference)
//
#include <hip/hip_runtime.h>
#include <hip/hip_bf16.h>

// DOMINANT GCN autoencoder on MI355X.
// R8 changes:
//  (1) Feature-split aggregation: gather tables stored as two contiguous
//      3.2 MB halves (feats 0-31 / 32-63); each aggregate = two sequential
//      half-passes whose working set fits the 4 MiB per-XCD L2.
//      64 B rows -> quarter-wave gathers (4 edges per load instruction).
//  (2) GEMM float4-K inner loop (LDA=K+4, 16B-aligned LDS rows).
// Base: R7 = 334us.

// ---------------- CSR build ----------------

__global__ __launch_bounds__(256) void init_k(int* __restrict__ deg,
                                              int* __restrict__ cnt,
                                              int Npad, int N) {
    int i = blockIdx.x * 256 + threadIdx.x;
    if (i < Npad) deg[i] = 0;
    if (i < N)    cnt[i] = 0;
}

__global__ __launch_bounds__(256) void hist_deg(const int* __restrict__ dst,
                                                int* __restrict__ deg, int E) {
    int e = blockIdx.x * 256 + threadIdx.x;
    if (e < E) atomicAdd(&deg[dst[e]], 1);
}

__global__ __launch_bounds__(256) void scan_phase1(const int* __restrict__ deg,
                                                   int* __restrict__ block_sums) {
    int b = blockIdx.x, t = threadIdx.x;
    const int4* p = reinterpret_cast<const int4*>(deg + (size_t)b * 2048);
    int4 a = p[t * 2], c = p[t * 2 + 1];
    int s = a.x + a.y + a.z + a.w + c.x + c.y + c.z + c.w;
#pragma unroll
    for (int off = 32; off; off >>= 1) s += __shfl_down(s, off);
    __shared__ int wsum[4];
    if ((t & 63) == 0) wsum[t >> 6] = s;
    __syncthreads();
    if (t == 0) block_sums[b] = wsum[0] + wsum[1] + wsum[2] + wsum[3];
}

__global__ __launch_bounds__(256) void scan_phase2(const int* __restrict__ block_sums,
                                                   int* __restrict__ block_off,
                                                   int* __restrict__ row_ptr,
                                                   int B, int N) {
    __shared__ int s[256];
    int t = threadIdx.x;
    int v = (t < B) ? block_sums[t] : 0;
    s[t] = v;
    __syncthreads();
#pragma unroll
    for (int off = 1; off < 256; off <<= 1) {
        int u = (t >= off) ? s[t - off] : 0;
        __syncthreads();
        s[t] += u;
        __syncthreads();
    }
    if (t < B) block_off[t] = s[t] - v;
    if (t == 255) row_ptr[N] = s[255];
}

__global__ __launch_bounds__(256) void scan_phase3(const int* __restrict__ deg,
                                                   const int* __restrict__ block_off,
                                                   int* __restrict__ row_ptr,
                                                   float* __restrict__ dis, int N) {
    int b = blockIdx.x, t = threadIdx.x;
    int base = b * 2048 + t * 8;
    const int4* p = reinterpret_cast<const int4*>(deg + base);
    int4 a = p[0], c = p[1];
    int d[8] = {a.x, a.y, a.z, a.w, c.x, c.y, c.z, c.w};
    int pre[8], s = 0;
#pragma unroll
    for (int j = 0; j < 8; ++j) { pre[j] = s; s += d[j]; }
    __shared__ int ls[256];
    ls[t] = s;
    __syncthreads();
#pragma unroll
    for (int off = 1; off < 256; off <<= 1) {
        int u = (t >= off) ? ls[t - off] : 0;
        __syncthreads();
        ls[t] += u;
        __syncthreads();
    }
    int excl = ls[t] - s + block_off[b];
#pragma unroll
    for (int j = 0; j < 8; ++j) {
        int i = base + j;
        if (i < N) {
            row_ptr[i] = excl + pre[j];
            dis[i] = rsqrtf((float)(d[j] + 1));
        }
    }
}

__global__ __launch_bounds__(256) void fill_csr(const int* __restrict__ src,
                                                const int* __restrict__ dst,
                                                const int* __restrict__ row_ptr,
                                                int* __restrict__ cnt,
                                                int* __restrict__ csr_src, int E) {
    int e = blockIdx.x * 256 + threadIdx.x;
    if (e < E) {
        int d = dst[e];
        int pos = row_ptr[d] + atomicAdd(&cnt[d], 1);
        csr_src[pos] = src[e];
    }
}

// ---------------- helpers ----------------

__device__ __forceinline__ ushort r16(float f) {
    __hip_bfloat16 h = __float2bfloat16(f);   // round-to-nearest-even
    return *reinterpret_cast<ushort*>(&h);
}
__device__ __forceinline__ float bf_lo(unsigned u) {
    return __builtin_bit_cast(float, u << 16);
}
__device__ __forceinline__ float bf_hi(unsigned u) {
    return __builtin_bit_cast(float, u & 0xFFFF0000u);
}

// ---------------- GEMM, row-scale + split bf16 tables ----------------
// Glo[r][0..31] / Ghi[r][0..31] = bf16( dis[r] * (A @ W)[r][c] ), DOUT=64.
template <int K>
__global__ __launch_bounds__(256) void gemm_scale(const float* __restrict__ A,
                                                  const float* __restrict__ W,
                                                  const float* __restrict__ dis,
                                                  ushort* __restrict__ Glo,
                                                  ushort* __restrict__ Ghi, int N) {
    constexpr int DOUT = 64;
    constexpr int CG   = DOUT / 4;       // 16 col-groups
    constexpr int RG   = 256 / CG;       // 16 row-groups
    constexpr int ROWS = RG * 4;         // 64 rows/block
    constexpr int LDA  = K + 4;          // 16B-aligned rows, breaks bank stride

    __shared__ __align__(16) float a_lds[ROWS * LDA];
    __shared__ __align__(16) float w_lds[K * DOUT];

    int t    = threadIdx.x;
    int row0 = blockIdx.x * ROWS;

    constexpr int WF4 = K * DOUT / 4;
    for (int q = t; q < WF4; q += 256)
        reinterpret_cast<float4*>(w_lds)[q] =
            reinterpret_cast<const float4*>(W)[q];

    constexpr int AF4 = ROWS * K / 4;
    for (int q = t; q < AF4; q += 256) {
        int r  = q / (K / 4);
        int kc = q % (K / 4);
        float4 v = make_float4(0.f, 0.f, 0.f, 0.f);
        int gr = row0 + r;
        if (gr < N)
            v = reinterpret_cast<const float4*>(A + (size_t)gr * K)[kc];
        *reinterpret_cast<float4*>(&a_lds[r * LDA + kc * 4]) = v;
    }
    __syncthreads();

    int c0 = (t % CG) * 4;
    int r0 = (t / CG) * 4;

    float4 acc[4] = {};
    for (int k = 0; k < K; k += 4) {
        float4 w0 = *reinterpret_cast<const float4*>(&w_lds[(k + 0) * DOUT + c0]);
        float4 w1 = *reinterpret_cast<const float4*>(&w_lds[(k + 1) * DOUT + c0]);
        float4 w2 = *reinterpret_cast<const float4*>(&w_lds[(k + 2) * DOUT + c0]);
        float4 w3 = *reinterpret_cast<const float4*>(&w_lds[(k + 3) * DOUT + c0]);
#pragma unroll
        for (int j = 0; j < 4; ++j) {
            float4 a4 = *reinterpret_cast<const float4*>(&a_lds[(r0 + j) * LDA + k]);
            acc[j].x += a4.x * w0.x + a4.y * w1.x + a4.z * w2.x + a4.w * w3.x;
            acc[j].y += a4.x * w0.y + a4.y * w1.y + a4.z * w2.y + a4.w * w3.y;
            acc[j].z += a4.x * w0.z + a4.y * w1.z + a4.z * w2.z + a4.w * w3.z;
            acc[j].w += a4.x * w0.w + a4.y * w1.w + a4.z * w2.w + a4.w * w3.w;
        }
    }

    ushort* Gh = (c0 < 32) ? Glo : Ghi;
    int ch = c0 & 31;
#pragma unroll
    for (int j = 0; j < 4; ++j) {
        int gr = row0 + r0 + j;
        if (gr < N) {
            float s = dis[gr];
            float4 o = acc[j];
            ushort4 pk;
            pk.x = r16(o.x * s); pk.y = r16(o.y * s);
            pk.z = r16(o.z * s); pk.w = r16(o.w * s);
            *reinterpret_cast<ushort4*>(&Gh[(size_t)gr * 32 + ch]) = pk;
        }
    }
}

// ---------------- GEMM, bias epilogue, fp32 out (final layer) ----------------
template <int K, int DOUT>
__global__ __launch_bounds__(256) void gemm_bias(const float* __restrict__ A,
                                                 const float* __restrict__ W,
                                                 const float* __restrict__ bias,
                                                 float* __restrict__ Out, int N) {
    constexpr int CG   = DOUT / 4;
    constexpr int RG   = 256 / CG;
    constexpr int ROWS = RG * 4;
    constexpr int LDA  = K + 4;

    __shared__ __align__(16) float a_lds[ROWS * LDA];
    __shared__ __align__(16) float w_lds[K * DOUT];

    int t    = threadIdx.x;
    int row0 = blockIdx.x * ROWS;

    constexpr int WF4 = K * DOUT / 4;
    for (int q = t; q < WF4; q += 256)
        reinterpret_cast<float4*>(w_lds)[q] =
            reinterpret_cast<const float4*>(W)[q];

    constexpr int AF4 = ROWS * K / 4;
    for (int q = t; q < AF4; q += 256) {
        int r  = q / (K / 4);
        int kc = q % (K / 4);
        float4 v = make_float4(0.f, 0.f, 0.f, 0.f);
        int gr = row0 + r;
        if (gr < N)
            v = reinterpret_cast<const float4*>(A + (size_t)gr * K)[kc];
        *reinterpret_cast<float4*>(&a_lds[r * LDA + kc * 4]) = v;
    }
    __syncthreads();

    int c0 = (t % CG) * 4;
    int r0 = (t / CG) * 4;

    float4 acc[4] = {};
    for (int k = 0; k < K; k += 4) {
        float4 w0 = *reinterpret_cast<const float4*>(&w_lds[(k + 0) * DOUT + c0]);
        float4 w1 = *reinterpret_cast<const float4*>(&w_lds[(k + 1) * DOUT + c0]);
        float4 w2 = *reinterpret_cast<const float4*>(&w_lds[(k + 2) * DOUT + c0]);
        float4 w3 = *reinterpret_cast<const float4*>(&w_lds[(k + 3) * DOUT + c0]);
#pragma unroll
        for (int j = 0; j < 4; ++j) {
            float4 a4 = *reinterpret_cast<const float4*>(&a_lds[(r0 + j) * LDA + k]);
            acc[j].x += a4.x * w0.x + a4.y * w1.x + a4.z * w2.x + a4.w * w3.x;
            acc[j].y += a4.x * w0.y + a4.y * w1.y + a4.z * w2.y + a4.w * w3.y;
            acc[j].z += a4.x * w0.z + a4.y * w1.z + a4.z * w2.z + a4.w * w3.z;
            acc[j].w += a4.x * w0.w + a4.y * w1.w + a4.z * w2.w + a4.w * w3.w;
        }
    }

    float4 b4v = *reinterpret_cast<const float4*>(&bias[c0]);
#pragma unroll
    for (int j = 0; j < 4; ++j) {
        int gr = row0 + r0 + j;
        if (gr < N) {
            float4 o = acc[j];
            o.x += b4v.x; o.y += b4v.y; o.z += b4v.z; o.w += b4v.w;
            reinterpret_cast<float4*>(Out + (size_t)gr * DOUT)[c0 / 4] = o;
        }
    }
}

// ---------------- Half-feature aggregation (quarter-wave gathers) ----------
// G: [N][16] uints = 32 bf16 features (one 64 B row per node). Quarter-wave:
// lane = q*16+fu; quarter q gathers edges q, q+4, q+8, ... (4 edges per wave
// load inst). Cross-quarter reduce via shfl_xor(16|32).
// v = dis[n] * (G[n] + sum_src G[src]) [+ bias[off..]] [relu]
// OUT16: OutV = half-table [N][16] uints, store bf16(dis[n]*v) pairs.
// else:  OutV = full-width fp32 [N][64], columns [off, off+32).
template <bool RELU, bool OUT16, bool BIAS>
__global__ __launch_bounds__(256) void aggregate_h(const unsigned* __restrict__ G,
                                                   const int* __restrict__ row_ptr,
                                                   const int* __restrict__ csr_src,
                                                   const float* __restrict__ dis,
                                                   const float* __restrict__ bias,
                                                   void* __restrict__ OutV,
                                                   int off, int N) {
    int wave = threadIdx.x >> 6;
    int lane = threadIdx.x & 63;
    int n = blockIdx.x * 4 + wave;
    if (n >= N) return;

    int q  = lane >> 4;        // edge slot (0..3)
    int fu = lane & 15;        // uint index within 64 B row

    int beg = row_ptr[n];
    int len = row_ptr[n + 1] - beg;
    int cnt = (len - q + 3) >> 2;          // my quarter's edge count
    const int* ep = csr_src + beg + q;     // my edges: ep[4k]

    float lo0 = 0.f, lo1 = 0.f, lo2 = 0.f, lo3 = 0.f;
    float hi0 = 0.f, hi1 = 0.f, hi2 = 0.f, hi3 = 0.f;

    int k = 0;
    for (; k + 4 <= cnt; k += 4) {
        int s0 = ep[4 * k],     s1 = ep[4 * k + 4];
        int s2 = ep[4 * k + 8], s3 = ep[4 * k + 12];
        unsigned u0 = G[(size_t)s0 * 16 + fu];
        unsigned u1 = G[(size_t)s1 * 16 + fu];
        unsigned u2 = G[(size_t)s2 * 16 + fu];
        unsigned u3 = G[(size_t)s3 * 16 + fu];
        lo0 += bf_lo(u0);  hi0 += bf_hi(u0);
        lo1 += bf_lo(u1);  hi1 += bf_hi(u1);
        lo2 += bf_lo(u2);  hi2 += bf_hi(u2);
        lo3 += bf_lo(u3);  hi3 += bf_hi(u3);
    }
    for (; k < cnt; ++k) {
        unsigned u = G[(size_t)ep[4 * k] * 16 + fu];
        lo1 += bf_lo(u);  hi1 += bf_hi(u);
    }

    float lo = (lo0 + lo1) + (lo2 + lo3);
    float hi = (hi0 + hi1) + (hi2 + hi3);
    lo += __shfl_xor(lo, 16);  hi += __shfl_xor(hi, 16);
    lo += __shfl_xor(lo, 32);  hi += __shfl_xor(hi, 32);

    if (q == 0) {
        unsigned us = G[(size_t)n * 16 + fu];   // self-loop pair
        float dn = dis[n];
        float vlo = dn * (lo + bf_lo(us));
        float vhi = dn * (hi + bf_hi(us));
        if (BIAS) {
            float2 b2 = reinterpret_cast<const float2*>(bias + off)[fu];
            vlo += b2.x;  vhi += b2.y;
        }
        if (RELU) { vlo = fmaxf(vlo, 0.f); vhi = fmaxf(vhi, 0.f); }
        if (OUT16) {
            // s3 half-table stores bf16(dis[n]*v) (reassociated layer-4 input)
            unsigned pk = (unsigned)r16(dn * vlo) | ((unsigned)r16(dn * vhi) << 16);
            ((unsigned*)OutV)[(size_t)n * 16 + fu] = pk;
        } else {
            reinterpret_cast<float2*>((float*)OutV + (size_t)n * 64 + off)[fu] =
                make_float2(vlo, vhi);
        }
    }
}

// ---------------- Launch ----------------

extern "C" void kernel_launch(void* const* d_in, const int* in_sizes, int n_in,
                              void* d_out, int out_size, void* d_ws, size_t ws_size,
                              hipStream_t stream) {
    const float* x     = (const float*)d_in[0];
    const int*   edges = (const int*)d_in[1];   // [2, E] row-major
    const float* W1 = (const float*)d_in[2];
    const float* b1 = (const float*)d_in[3];
    const float* W2 = (const float*)d_in[4];
    const float* b2 = (const float*)d_in[5];
    const float* W3 = (const float*)d_in[6];
    const float* b3 = (const float*)d_in[7];
    const float* W4 = (const float*)d_in[8];
    const float* b4 = (const float*)d_in[9];

    const int DIN = 128, DH = 64;
    int N = in_sizes[0] / DIN;
    int E = in_sizes[1] / 2;

    const int* e_src = edges;
    const int* e_dst = edges + E;

    float* out   = (float*)d_out;
    float* x_hat = out;                       // [N,128]
    float* z     = out + (size_t)N * DIN;     // [N,64]

    int B    = (N + 2047) / 2048;
    int Npad = B * 2048;

    char*  ws  = (char*)d_ws;
    size_t woff = 0;
    auto carve = [&](size_t bytes) {
        void* p = ws + woff;
        woff = (woff + bytes + 255) & ~(size_t)255;
        return p;
    };
    float*  dis        = (float*) carve((size_t)N * 4);
    int*    deg        = (int*)   carve((size_t)Npad * 4);
    int*    cnt        = (int*)   carve((size_t)N * 4);
    int*    row_ptr    = (int*)   carve((size_t)(N + 1) * 4);
    int*    csr_src    = (int*)   carve((size_t)E * 4);
    int*    block_sums = (int*)   carve((size_t)B * 4);
    int*    block_off  = (int*)   carve((size_t)B * 4);
    ushort* g_lo       = (ushort*)carve((size_t)N * 32 * 2);   // 3.2 MB half-table
    ushort* g_hi       = (ushort*)carve((size_t)N * 32 * 2);
    ushort* s3_lo      = (ushort*)carve((size_t)N * 32 * 2);   // layer-3 scaled out
    ushort* s3_hi      = (ushort*)carve((size_t)N * 32 * 2);
    float*  t          = (float*) carve((size_t)N * DH * 4);   // layer-4 agg result
    float*  act        = (float*) carve((size_t)N * DH * 4);   // h (layer-1 out)
    (void)ws_size;

    int nb_e   = (E + 255) / 256;
    int nb_agg = (N + 3) / 4;

    // CSR build
    init_k<<<(Npad + 255) / 256, 256, 0, stream>>>(deg, cnt, Npad, N);
    hist_deg<<<nb_e, 256, 0, stream>>>(e_dst, deg, E);
    scan_phase1<<<B, 256, 0, stream>>>(deg, block_sums);
    scan_phase2<<<1, 256, 0, stream>>>(block_sums, block_off, row_ptr, B, N);
    scan_phase3<<<B, 256, 0, stream>>>(deg, block_off, row_ptr, dis, N);
    fill_csr<<<nb_e, 256, 0, stream>>>(e_src, e_dst, row_ptr, cnt, csr_src, E);

    // Layer 1: h = relu(dis*(sum g1)+b1) -> act (fp32 full-width)
    gemm_scale<128><<<(N + 63) / 64, 256, 0, stream>>>(x, W1, dis, g_lo, g_hi, N);
    aggregate_h<true, false, true><<<nb_agg, 256, 0, stream>>>(
        (const unsigned*)g_lo, row_ptr, csr_src, dis, b1, act, 0, N);
    aggregate_h<true, false, true><<<nb_agg, 256, 0, stream>>>(
        (const unsigned*)g_hi, row_ptr, csr_src, dis, b1, act, 32, N);

    // Layer 2: z -> d_out (fp32 full-width)
    gemm_scale<64><<<(N + 63) / 64, 256, 0, stream>>>(act, W2, dis, g_lo, g_hi, N);
    aggregate_h<true, false, true><<<nb_agg, 256, 0, stream>>>(
        (const unsigned*)g_lo, row_ptr, csr_src, dis, b2, z, 0, N);
    aggregate_h<true, false, true><<<nb_agg, 256, 0, stream>>>(
        (const unsigned*)g_hi, row_ptr, csr_src, dis, b2, z, 32, N);

    // Layer 3: s3 = bf16(dis * relu(...)) half-tables
    gemm_scale<64><<<(N + 63) / 64, 256, 0, stream>>>(z, W3, dis, g_lo, g_hi, N);
    aggregate_h<true, true, true><<<nb_agg, 256, 0, stream>>>(
        (const unsigned*)g_lo, row_ptr, csr_src, dis, b3, s3_lo, 0, N);
    aggregate_h<true, true, true><<<nb_agg, 256, 0, stream>>>(
        (const unsigned*)g_hi, row_ptr, csr_src, dis, b3, s3_hi, 32, N);

    // Layer 4 (reassociated): t = dis*(s3[n] + sum s3[src]); x_hat = t W4 + b4
    aggregate_h<false, false, false><<<nb_agg, 256, 0, stream>>>(
        (const unsigned*)s3_lo, row_ptr, csr_src, dis, nullptr, t, 0, N);
    aggregate_h<false, false, false><<<nb_agg, 256, 0, stream>>>(
        (const unsigned*)s3_hi, row_ptr, csr_src, dis, nullptr, t, 32, N);
    gemm_bias<64, 128><<<(N + 31) / 32, 256, 0, stream>>>(t, W4, b4, x_hat, N);
}

// Round 9
// 335.105 us; speedup vs baseline: 1.4419x; 1.4419x over previous
//
#include <hip/hip_runtime.h>
#include <hip/hip_bf16.h>

// DOMINANT GCN autoencoder on MI355X.
// R9 = R7 structure (334us) + two controlled changes:
//  (1) GEMM float4-K inner loop with #pragma unroll 1 (R8's version minus the
//      VGPR blowup: R8 fully unrolled K -> 256 VGPR, 8.8% occupancy, +150us).
//  (2) fill_csr uses atomicSub on deg (dead after scan) -> cnt array removed.
// Aggregates: R7 half-wave bf16 version unchanged (at the ~3.3 TB/s
// random-gather ceiling; R7/R8 falsified concurrency and L2-fit theories).

// ---------------- CSR build ----------------

__global__ __launch_bounds__(256) void init_k(int* __restrict__ deg, int Npad) {
    int i = blockIdx.x * 256 + threadIdx.x;
    if (i < Npad) deg[i] = 0;
}

__global__ __launch_bounds__(256) void hist_deg(const int* __restrict__ dst,
                                                int* __restrict__ deg, int E) {
    int e = blockIdx.x * 256 + threadIdx.x;
    if (e < E) atomicAdd(&deg[dst[e]], 1);
}

__global__ __launch_bounds__(256) void scan_phase1(const int* __restrict__ deg,
                                                   int* __restrict__ block_sums) {
    int b = blockIdx.x, t = threadIdx.x;
    const int4* p = reinterpret_cast<const int4*>(deg + (size_t)b * 2048);
    int4 a = p[t * 2], c = p[t * 2 + 1];
    int s = a.x + a.y + a.z + a.w + c.x + c.y + c.z + c.w;
#pragma unroll
    for (int off = 32; off; off >>= 1) s += __shfl_down(s, off);
    __shared__ int wsum[4];
    if ((t & 63) == 0) wsum[t >> 6] = s;
    __syncthreads();
    if (t == 0) block_sums[b] = wsum[0] + wsum[1] + wsum[2] + wsum[3];
}

__global__ __launch_bounds__(256) void scan_phase2(const int* __restrict__ block_sums,
                                                   int* __restrict__ block_off,
                                                   int* __restrict__ row_ptr,
                                                   int B, int N) {
    __shared__ int s[256];
    int t = threadIdx.x;
    int v = (t < B) ? block_sums[t] : 0;
    s[t] = v;
    __syncthreads();
#pragma unroll
    for (int off = 1; off < 256; off <<= 1) {
        int u = (t >= off) ? s[t - off] : 0;
        __syncthreads();
        s[t] += u;
        __syncthreads();
    }
    if (t < B) block_off[t] = s[t] - v;
    if (t == 255) row_ptr[N] = s[255];
}

__global__ __launch_bounds__(256) void scan_phase3(const int* __restrict__ deg,
                                                   const int* __restrict__ block_off,
                                                   int* __restrict__ row_ptr,
                                                   float* __restrict__ dis, int N) {
    int b = blockIdx.x, t = threadIdx.x;
    int base = b * 2048 + t * 8;
    const int4* p = reinterpret_cast<const int4*>(deg + base);
    int4 a = p[0], c = p[1];
    int d[8] = {a.x, a.y, a.z, a.w, c.x, c.y, c.z, c.w};
    int pre[8], s = 0;
#pragma unroll
    for (int j = 0; j < 8; ++j) { pre[j] = s; s += d[j]; }
    __shared__ int ls[256];
    ls[t] = s;
    __syncthreads();
#pragma unroll
    for (int off = 1; off < 256; off <<= 1) {
        int u = (t >= off) ? ls[t - off] : 0;
        __syncthreads();
        ls[t] += u;
        __syncthreads();
    }
    int excl = ls[t] - s + block_off[b];
#pragma unroll
    for (int j = 0; j < 8; ++j) {
        int i = base + j;
        if (i < N) {
            row_ptr[i] = excl + pre[j];
            dis[i] = rsqrtf((float)(d[j] + 1));
        }
    }
}

// Positions fill each row back-to-front via atomicSub on deg (deg is dead
// after scan_phase3; saves the separate cnt array + its init).
__global__ __launch_bounds__(256) void fill_csr(const int* __restrict__ src,
                                                const int* __restrict__ dst,
                                                const int* __restrict__ row_ptr,
                                                int* __restrict__ deg,
                                                int* __restrict__ csr_src, int E) {
    int e = blockIdx.x * 256 + threadIdx.x;
    if (e < E) {
        int d = dst[e];
        int old = atomicSub(&deg[d], 1);
        csr_src[row_ptr[d] + old - 1] = src[e];
    }
}

// ---------------- helpers ----------------

__device__ __forceinline__ ushort r16(float f) {
    __hip_bfloat16 h = __float2bfloat16(f);   // round-to-nearest-even
    return *reinterpret_cast<ushort*>(&h);
}
__device__ __forceinline__ float bf_lo(unsigned u) {   // feature 2f (low ushort)
    return __builtin_bit_cast(float, u << 16);
}
__device__ __forceinline__ float bf_hi(unsigned u) {   // feature 2f+1
    return __builtin_bit_cast(float, u & 0xFFFF0000u);
}

// ---------------- GEMM, row-scale + bf16 epilogue ----------------
// G16[r][c] = bf16( dis[r] * sum_k A[r][k] * W[k][c] )
// float4-K inner loop, unroll 1 to cap VGPR (R8 lesson: full unroll -> 256).
template <int K, int DOUT>
__global__ __launch_bounds__(256) void gemm_scale(const float* __restrict__ A,
                                                  const float* __restrict__ W,
                                                  const float* __restrict__ dis,
                                                  ushort* __restrict__ G16, int N) {
    constexpr int CG   = DOUT / 4;
    constexpr int RG   = 256 / CG;
    constexpr int ROWS = RG * 4;
    constexpr int LDA  = K + 4;          // 16B-aligned padded rows

    __shared__ __align__(16) float a_lds[ROWS * LDA];
    __shared__ __align__(16) float w_lds[K * DOUT];

    int t    = threadIdx.x;
    int row0 = blockIdx.x * ROWS;

    constexpr int WF4 = K * DOUT / 4;
    for (int q = t; q < WF4; q += 256)
        reinterpret_cast<float4*>(w_lds)[q] =
            reinterpret_cast<const float4*>(W)[q];

    constexpr int AF4 = ROWS * K / 4;
    for (int q = t; q < AF4; q += 256) {
        int r  = q / (K / 4);
        int kc = q % (K / 4);
        float4 v = make_float4(0.f, 0.f, 0.f, 0.f);
        int gr = row0 + r;
        if (gr < N)
            v = reinterpret_cast<const float4*>(A + (size_t)gr * K)[kc];
        *reinterpret_cast<float4*>(&a_lds[r * LDA + kc * 4]) = v;
    }
    __syncthreads();

    int c0 = (t % CG) * 4;
    int r0 = (t / CG) * 4;

    float4 acc[4] = {};
#pragma unroll 1
    for (int k = 0; k < K; k += 4) {
        float4 w0 = *reinterpret_cast<const float4*>(&w_lds[(k + 0) * DOUT + c0]);
        float4 w1 = *reinterpret_cast<const float4*>(&w_lds[(k + 1) * DOUT + c0]);
        float4 w2 = *reinterpret_cast<const float4*>(&w_lds[(k + 2) * DOUT + c0]);
        float4 w3 = *reinterpret_cast<const float4*>(&w_lds[(k + 3) * DOUT + c0]);
#pragma unroll
        for (int j = 0; j < 4; ++j) {
            float4 a4 = *reinterpret_cast<const float4*>(&a_lds[(r0 + j) * LDA + k]);
            acc[j].x += a4.x * w0.x + a4.y * w1.x + a4.z * w2.x + a4.w * w3.x;
            acc[j].y += a4.x * w0.y + a4.y * w1.y + a4.z * w2.y + a4.w * w3.y;
            acc[j].z += a4.x * w0.z + a4.y * w1.z + a4.z * w2.z + a4.w * w3.z;
            acc[j].w += a4.x * w0.w + a4.y * w1.w + a4.z * w2.w + a4.w * w3.w;
        }
    }

#pragma unroll
    for (int j = 0; j < 4; ++j) {
        int gr = row0 + r0 + j;
        if (gr < N) {
            float s = dis[gr];
            float4 o = acc[j];
            ushort4 pk;
            pk.x = r16(o.x * s); pk.y = r16(o.y * s);
            pk.z = r16(o.z * s); pk.w = r16(o.w * s);
            *reinterpret_cast<ushort4*>(&G16[(size_t)gr * DOUT + c0]) = pk;
        }
    }
}

// ---------------- GEMM, bias epilogue, fp32 out (final layer) ----------------
template <int K, int DOUT>
__global__ __launch_bounds__(256) void gemm_bias(const float* __restrict__ A,
                                                 const float* __restrict__ W,
                                                 const float* __restrict__ bias,
                                                 float* __restrict__ Out, int N) {
    constexpr int CG   = DOUT / 4;
    constexpr int RG   = 256 / CG;
    constexpr int ROWS = RG * 4;
    constexpr int LDA  = K + 4;

    __shared__ __align__(16) float a_lds[ROWS * LDA];
    __shared__ __align__(16) float w_lds[K * DOUT];

    int t    = threadIdx.x;
    int row0 = blockIdx.x * ROWS;

    constexpr int WF4 = K * DOUT / 4;
    for (int q = t; q < WF4; q += 256)
        reinterpret_cast<float4*>(w_lds)[q] =
            reinterpret_cast<const float4*>(W)[q];

    constexpr int AF4 = ROWS * K / 4;
    for (int q = t; q < AF4; q += 256) {
        int r  = q / (K / 4);
        int kc = q % (K / 4);
        float4 v = make_float4(0.f, 0.f, 0.f, 0.f);
        int gr = row0 + r;
        if (gr < N)
            v = reinterpret_cast<const float4*>(A + (size_t)gr * K)[kc];
        *reinterpret_cast<float4*>(&a_lds[r * LDA + kc * 4]) = v;
    }
    __syncthreads();

    int c0 = (t % CG) * 4;
    int r0 = (t / CG) * 4;

    float4 acc[4] = {};
#pragma unroll 1
    for (int k = 0; k < K; k += 4) {
        float4 w0 = *reinterpret_cast<const float4*>(&w_lds[(k + 0) * DOUT + c0]);
        float4 w1 = *reinterpret_cast<const float4*>(&w_lds[(k + 1) * DOUT + c0]);
        float4 w2 = *reinterpret_cast<const float4*>(&w_lds[(k + 2) * DOUT + c0]);
        float4 w3 = *reinterpret_cast<const float4*>(&w_lds[(k + 3) * DOUT + c0]);
#pragma unroll
        for (int j = 0; j < 4; ++j) {
            float4 a4 = *reinterpret_cast<const float4*>(&a_lds[(r0 + j) * LDA + k]);
            acc[j].x += a4.x * w0.x + a4.y * w1.x + a4.z * w2.x + a4.w * w3.x;
            acc[j].y += a4.x * w0.y + a4.y * w1.y + a4.z * w2.y + a4.w * w3.y;
            acc[j].z += a4.x * w0.z + a4.y * w1.z + a4.z * w2.z + a4.w * w3.z;
            acc[j].w += a4.x * w0.w + a4.y * w1.w + a4.z * w2.w + a4.w * w3.w;
        }
    }

    float4 b4v = *reinterpret_cast<const float4*>(&bias[c0]);
#pragma unroll
    for (int j = 0; j < 4; ++j) {
        int gr = row0 + r0 + j;
        if (gr < N) {
            float4 o = acc[j];
            o.x += b4v.x; o.y += b4v.y; o.z += b4v.z; o.w += b4v.w;
            reinterpret_cast<float4*>(Out + (size_t)gr * DOUT)[c0 / 4] = o;
        }
    }
}

// ---------------- Aggregation (half-wave uint gathers, D=64) ----------------
// Identical to R7 (known-good). v = dis[n]*(G[n]+sum_src G[src]) [+bias][relu];
// OUT16 stores bf16(dis[n]*v) pairs for the reassociated layer-4 table.
template <bool RELU, bool OUT16, bool BIAS>
__global__ __launch_bounds__(256) void aggregate_bf64(const unsigned* __restrict__ G,
                                                      const int* __restrict__ row_ptr,
                                                      const int* __restrict__ csr_src,
                                                      const float* __restrict__ dis,
                                                      const float* __restrict__ bias,
                                                      void* __restrict__ OutV, int N) {
    int wave = threadIdx.x >> 6;
    int lane = threadIdx.x & 63;
    int n = blockIdx.x * 4 + wave;
    if (n >= N) return;

    int h  = lane >> 5;        // half-wave (edge parity)
    int fl = lane & 31;        // feature pair index

    int beg = row_ptr[n];
    int len = row_ptr[n + 1] - beg;
    int cnt = (len - h + 1) >> 1;
    const int* ep = csr_src + beg + h;

    float lo0 = 0.f, lo1 = 0.f, lo2 = 0.f, lo3 = 0.f;
    float hi0 = 0.f, hi1 = 0.f, hi2 = 0.f, hi3 = 0.f;

    int k = 0;
    for (; k + 8 <= cnt; k += 8) {
        int s0 = ep[2 * k],      s1 = ep[2 * k + 2];
        int s2 = ep[2 * k + 4],  s3 = ep[2 * k + 6];
        int s4 = ep[2 * k + 8],  s5 = ep[2 * k + 10];
        int s6 = ep[2 * k + 12], s7 = ep[2 * k + 14];
        unsigned u0 = G[(size_t)s0 * 32 + fl];
        unsigned u1 = G[(size_t)s1 * 32 + fl];
        unsigned u2 = G[(size_t)s2 * 32 + fl];
        unsigned u3 = G[(size_t)s3 * 32 + fl];
        unsigned u4 = G[(size_t)s4 * 32 + fl];
        unsigned u5 = G[(size_t)s5 * 32 + fl];
        unsigned u6 = G[(size_t)s6 * 32 + fl];
        unsigned u7 = G[(size_t)s7 * 32 + fl];
        lo0 += bf_lo(u0) + bf_lo(u4);  hi0 += bf_hi(u0) + bf_hi(u4);
        lo1 += bf_lo(u1) + bf_lo(u5);  hi1 += bf_hi(u1) + bf_hi(u5);
        lo2 += bf_lo(u2) + bf_lo(u6);  hi2 += bf_hi(u2) + bf_hi(u6);
        lo3 += bf_lo(u3) + bf_lo(u7);  hi3 += bf_hi(u3) + bf_hi(u7);
    }
    for (; k + 4 <= cnt; k += 4) {
        int s0 = ep[2 * k],     s1 = ep[2 * k + 2];
        int s2 = ep[2 * k + 4], s3 = ep[2 * k + 6];
        unsigned u0 = G[(size_t)s0 * 32 + fl];
        unsigned u1 = G[(size_t)s1 * 32 + fl];
        unsigned u2 = G[(size_t)s2 * 32 + fl];
        unsigned u3 = G[(size_t)s3 * 32 + fl];
        lo0 += bf_lo(u0);  hi0 += bf_hi(u0);
        lo1 += bf_lo(u1);  hi1 += bf_hi(u1);
        lo2 += bf_lo(u2);  hi2 += bf_hi(u2);
        lo3 += bf_lo(u3);  hi3 += bf_hi(u3);
    }
    for (; k < cnt; ++k) {
        unsigned u = G[(size_t)ep[2 * k] * 32 + fl];
        lo1 += bf_lo(u);  hi1 += bf_hi(u);
    }

    float lo = (lo0 + lo1) + (lo2 + lo3);
    float hi = (hi0 + hi1) + (hi2 + hi3);
    lo += __shfl_xor(lo, 32);
    hi += __shfl_xor(hi, 32);

    if (h == 0) {
        unsigned us = G[(size_t)n * 32 + fl];   // self-loop pair
        float dn = dis[n];
        float vlo = dn * (lo + bf_lo(us));
        float vhi = dn * (hi + bf_hi(us));
        if (BIAS) {
            float2 b2 = reinterpret_cast<const float2*>(bias)[fl];
            vlo += b2.x;  vhi += b2.y;
        }
        if (RELU) { vlo = fmaxf(vlo, 0.f); vhi = fmaxf(vhi, 0.f); }
        if (OUT16) {
            // extra dn factor: s3 = bf16(dis[n]*v) for reassociated layer 4
            unsigned pk = (unsigned)r16(dn * vlo) | ((unsigned)r16(dn * vhi) << 16);
            ((unsigned*)OutV)[(size_t)n * 32 + fl] = pk;
        } else {
            reinterpret_cast<float2*>(OutV)[(size_t)n * 32 + fl] =
                make_float2(vlo, vhi);
        }
    }
}

// ---------------- Launch ----------------

extern "C" void kernel_launch(void* const* d_in, const int* in_sizes, int n_in,
                              void* d_out, int out_size, void* d_ws, size_t ws_size,
                              hipStream_t stream) {
    const float* x     = (const float*)d_in[0];
    const int*   edges = (const int*)d_in[1];   // [2, E] row-major
    const float* W1 = (const float*)d_in[2];
    const float* b1 = (const float*)d_in[3];
    const float* W2 = (const float*)d_in[4];
    const float* b2 = (const float*)d_in[5];
    const float* W3 = (const float*)d_in[6];
    const float* b3 = (const float*)d_in[7];
    const float* W4 = (const float*)d_in[8];
    const float* b4 = (const float*)d_in[9];

    const int DIN = 128, DH = 64;
    int N = in_sizes[0] / DIN;
    int E = in_sizes[1] / 2;

    const int* e_src = edges;
    const int* e_dst = edges + E;

    float* out   = (float*)d_out;
    float* x_hat = out;                       // [N,128]
    float* z     = out + (size_t)N * DIN;     // [N,64]

    int B    = (N + 2047) / 2048;
    int Npad = B * 2048;

    char*  ws  = (char*)d_ws;
    size_t woff = 0;
    auto carve = [&](size_t bytes) {
        void* p = ws + woff;
        woff = (woff + bytes + 255) & ~(size_t)255;
        return p;
    };
    float*  dis        = (float*) carve((size_t)N * 4);
    int*    deg        = (int*)   carve((size_t)Npad * 4);
    int*    row_ptr    = (int*)   carve((size_t)(N + 1) * 4);
    int*    csr_src    = (int*)   carve((size_t)E * 4);
    int*    block_sums = (int*)   carve((size_t)B * 4);
    int*    block_off  = (int*)   carve((size_t)B * 4);
    ushort* g16        = (ushort*)carve((size_t)N * DH * 2);   // gather table
    ushort* s3         = (ushort*)carve((size_t)N * DH * 2);   // layer-3 scaled out
    float*  t          = (float*) carve((size_t)N * DH * 4);   // layer-4 agg result
    float*  act        = (float*) carve((size_t)N * DH * 4);   // h (layer-1 out)
    (void)ws_size;

    int nb_e   = (E + 255) / 256;
    int nb_agg = (N + 3) / 4;

    // CSR build
    init_k<<<(Npad + 255) / 256, 256, 0, stream>>>(deg, Npad);
    hist_deg<<<nb_e, 256, 0, stream>>>(e_dst, deg, E);
    scan_phase1<<<B, 256, 0, stream>>>(deg, block_sums);
    scan_phase2<<<1, 256, 0, stream>>>(block_sums, block_off, row_ptr, B, N);
    scan_phase3<<<B, 256, 0, stream>>>(deg, block_off, row_ptr, dis, N);
    fill_csr<<<nb_e, 256, 0, stream>>>(e_src, e_dst, row_ptr, deg, csr_src, E);

    // Layer 1: h = relu(dis*(sum g1)+b1), g1 = dis*(x W1)
    gemm_scale<128, 64><<<(N + 63) / 64, 256, 0, stream>>>(x, W1, dis, g16, N);
    aggregate_bf64<true, false, true><<<nb_agg, 256, 0, stream>>>(
        (const unsigned*)g16, row_ptr, csr_src, dis, b1, act, N);

    // Layer 2: z = relu(...) -> d_out (fp32)
    gemm_scale<64, 64><<<(N + 63) / 64, 256, 0, stream>>>(act, W2, dis, g16, N);
    aggregate_bf64<true, false, true><<<nb_agg, 256, 0, stream>>>(
        (const unsigned*)g16, row_ptr, csr_src, dis, b2, z, N);

    // Layer 3: s3 = bf16(dis * relu(...))  (table for layer-4 aggregation)
    gemm_scale<64, 64><<<(N + 63) / 64, 256, 0, stream>>>(z, W3, dis, g16, N);
    aggregate_bf64<true, true, true><<<nb_agg, 256, 0, stream>>>(
        (const unsigned*)g16, row_ptr, csr_src, dis, b3, s3, N);

    // Layer 4 (reassociated): t = dis*(s3[n] + sum s3[src]);  x_hat = t W4 + b4
    aggregate_bf64<false, false, false><<<nb_agg, 256, 0, stream>>>(
        (const unsigned*)s3, row_ptr, csr_src, dis, nullptr, t, N);
    gemm_bias<64, 128><<<(N + 31) / 32, 256, 0, stream>>>(t, W4, b4, x_hat, N);
}